// Round 1
// baseline (1361.640 us; speedup 1.0000x reference)
//
#include <hip/hip_runtime.h>
#include <cstdint>
#include <cstddef>

#define D_MODEL 2048
#define D_FFN   8192
#define RANK    16
#define EPS     1e-6f
#define MOD_SCALE 0.1f

typedef float    f32x4 __attribute__((ext_vector_type(4)));
typedef _Float16 half8 __attribute__((ext_vector_type(8)));
typedef _Float16 half4 __attribute__((ext_vector_type(4)));

// Async global->LDS, 16B per lane. LDS dest must be wave-uniform-base + lane*16.
__device__ __forceinline__ void async_load16(const void* g, void* l) {
  __builtin_amdgcn_global_load_lds(
      (const __attribute__((address_space(1))) uint32_t*)g,
      (__attribute__((address_space(3))) uint32_t*)l,
      16, 0, 0);
}

// ---------------------------------------------------------------------------
// Kernel 1: per-token RMSNorm -> h (f16), and c[m,r] = (h.A)[r] * 0.1*tanh((attn.A)[r])
// One block (256 threads) per token; each thread owns 8 consecutive elements.
// ---------------------------------------------------------------------------
__global__ __launch_bounds__(256) void prep_kernel(
    const float* __restrict__ hs, const float* __restrict__ attn,
    const float* __restrict__ Amat, const float* __restrict__ gamma,
    _Float16* __restrict__ h16, float* __restrict__ cmat)
{
  const int token = blockIdx.x;
  const int tid   = threadIdx.x;
  const int lane  = tid & 63;
  const int wv    = tid >> 6;
  const size_t tb = (size_t)token * D_MODEL;
  const int base  = tid * 8;

  floatx4_fix:;
  f32x4 x0 = *(const f32x4*)(hs + tb + base);
  f32x4 x1 = *(const f32x4*)(hs + tb + base + 4);
  f32x4 a0 = *(const f32x4*)(attn + tb + base);
  f32x4 a1 = *(const f32x4*)(attn + tb + base + 4);

  float ss = 0.f;
  #pragma unroll
  for (int j = 0; j < 4; ++j) ss += x0[j]*x0[j] + x1[j]*x1[j];
  #pragma unroll
  for (int off = 32; off > 0; off >>= 1) ss += __shfl_xor(ss, off, 64);

  __shared__ float red[4];
  __shared__ float redp[4][RANK];
  __shared__ float redh[4][RANK];
  if (lane == 0) red[wv] = ss;
  __syncthreads();
  const float tot = red[0] + red[1] + red[2] + red[3];
  const float rms = rsqrtf(tot * (1.0f / D_MODEL) + EPS);

  f32x4 g0 = *(const f32x4*)(gamma + base);
  f32x4 g1 = *(const f32x4*)(gamma + base + 4);
  float hv[8], av[8];
  #pragma unroll
  for (int j = 0; j < 4; ++j) {
    hv[j]   = x0[j] * rms * g0[j];
    hv[4+j] = x1[j] * rms * g1[j];
    av[j]   = a0[j];
    av[4+j] = a1[j];
  }
  half8 hh;
  #pragma unroll
  for (int j = 0; j < 8; ++j) hh[j] = (_Float16)hv[j];
  *(half8*)(h16 + tb + base) = hh;

  float pa[RANK], ph[RANK];
  #pragma unroll
  for (int r = 0; r < RANK; ++r) { pa[r] = 0.f; ph[r] = 0.f; }
  #pragma unroll
  for (int e = 0; e < 8; ++e) {
    const f32x4* Ar = (const f32x4*)(Amat + (size_t)(base + e) * RANK);
    #pragma unroll
    for (int q = 0; q < 4; ++q) {
      f32x4 ar = Ar[q];
      #pragma unroll
      for (int j = 0; j < 4; ++j) {
        pa[q*4+j] += av[e] * ar[j];
        ph[q*4+j] += hv[e] * ar[j];
      }
    }
  }
  #pragma unroll
  for (int r = 0; r < RANK; ++r) {
    #pragma unroll
    for (int off = 32; off > 0; off >>= 1) {
      pa[r] += __shfl_xor(pa[r], off, 64);
      ph[r] += __shfl_xor(ph[r], off, 64);
    }
  }
  if (lane == 0) {
    #pragma unroll
    for (int r = 0; r < RANK; ++r) { redp[wv][r] = pa[r]; redh[wv][r] = ph[r]; }
  }
  __syncthreads();
  if (tid < RANK) {
    float sp = redp[0][tid] + redp[1][tid] + redp[2][tid] + redp[3][tid];
    float sh = redh[0][tid] + redh[1][tid] + redh[2][tid] + redh[3][tid];
    cmat[(size_t)token * RANK + tid] = sh * (MOD_SCALE * tanhf(sp));
  }
}

// ---------------------------------------------------------------------------
// Kernel 2: dual GEMM  gate = h@Wg^T (+ rank-16 delta via one extra MFMA step),
//           up = h@Wu^T ; t = silu(gate)*up  (f16 out).
// 128x128 tile, BK=64, 4 waves (each 64x64 via 4x4 of 16x16x32 f16 MFMA).
// ---------------------------------------------------------------------------
__global__ __launch_bounds__(256, 2) void gemm_gateup(
    const _Float16* __restrict__ h16,
    const float* __restrict__ Wg, const float* __restrict__ Wu,
    const float* __restrict__ cmat, const float* __restrict__ Bmat,
    _Float16* __restrict__ tmat)
{
  __shared__ __align__(16) _Float16 sA [128*64];
  __shared__ __align__(16) _Float16 sB1[128*64];
  __shared__ __align__(16) _Float16 sB2[128*64];

  const int tid  = threadIdx.x;
  const int lane = tid & 63;
  const int wv   = tid >> 6;
  const int wm   = (wv >> 1) * 64;
  const int wn   = (wv & 1) * 64;
  const int lr   = lane & 15;
  const int quad = lane >> 4;
  const int gm0  = blockIdx.y * 128;
  const int gn0  = blockIdx.x * 128;

  f32x4 accG[4][4], accU[4][4];
  #pragma unroll
  for (int i = 0; i < 4; ++i)
    #pragma unroll
    for (int j = 0; j < 4; ++j) {
      f32x4 z = {0.f, 0.f, 0.f, 0.f};
      accG[i][j] = z; accU[i][j] = z;
    }

  for (int kt = 0; kt < D_MODEL / 64; ++kt) {
    __syncthreads();
    // A tile (f16, async DMA): 128 rows x 64 k
    const _Float16* Ab = h16 + (size_t)gm0 * D_MODEL + kt * 64;
    #pragma unroll
    for (int j = 0; j < 4; ++j) {
      int idx = j * 256 + tid;            // 0..1023 16B-chunks
      int row = idx >> 3, c16 = idx & 7;
      async_load16(Ab + (size_t)row * D_MODEL + c16 * 8, &sA[idx * 8]);
    }
    // B tiles (fp32 -> f16 convert on the fly)
    const float* W1 = Wg + (size_t)gn0 * D_MODEL + kt * 64;
    const float* W2 = Wu + (size_t)gn0 * D_MODEL + kt * 64;
    #pragma unroll
    for (int i = 0; i < 8; ++i) {
      int idx = i * 256 + tid;            // 0..2047 float4-chunks
      int row = idx >> 4, c4 = idx & 15;
      f32x4 v1 = *(const f32x4*)(W1 + (size_t)row * D_MODEL + c4 * 4);
      f32x4 v2 = *(const f32x4*)(W2 + (size_t)row * D_MODEL + c4 * 4);
      half4 h1, h2;
      #pragma unroll
      for (int j = 0; j < 4; ++j) { h1[j] = (_Float16)v1[j]; h2[j] = (_Float16)v2[j]; }
      *(half4*)&sB1[row * 64 + c4 * 4] = h1;
      *(half4*)&sB2[row * 64 + c4 * 4] = h2;
    }
    __syncthreads();
    #pragma unroll
    for (int ks = 0; ks < 2; ++ks) {
      const int ko = ks * 32 + quad * 8;
      half8 af[4], bg[4], bu[4];
      #pragma unroll
      for (int im = 0; im < 4; ++im)
        af[im] = *(const half8*)&sA[(wm + im * 16 + lr) * 64 + ko];
      #pragma unroll
      for (int in = 0; in < 4; ++in) {
        bg[in] = *(const half8*)&sB1[(wn + in * 16 + lr) * 64 + ko];
        bu[in] = *(const half8*)&sB2[(wn + in * 16 + lr) * 64 + ko];
      }
      #pragma unroll
      for (int im = 0; im < 4; ++im)
        #pragma unroll
        for (int in = 0; in < 4; ++in) {
          accG[im][in] = __builtin_amdgcn_mfma_f32_16x16x32_f16(af[im], bg[in], accG[im][in], 0, 0, 0);
          accU[im][in] = __builtin_amdgcn_mfma_f32_16x16x32_f16(af[im], bu[in], accU[im][in], 0, 0, 0);
        }
    }
  }

  // rank-16 delta folded in as one zero-padded K=32 MFMA step into accG.
  // sA region <- c tile [128 x 32], sB1 region <- Bmat^T tile [128 x 32].
  __syncthreads();
  #pragma unroll
  for (int i = 0; i < 16; ++i) {
    int idx = i * 256 + tid;              // 0..4095
    int m = idx >> 5, kk = idx & 31;
    sA[idx]  = (kk < RANK) ? (_Float16)cmat[(size_t)(gm0 + m) * RANK + kk] : (_Float16)0.0f;
    sB1[idx] = (kk < RANK) ? (_Float16)Bmat[(size_t)kk * D_FFN + gn0 + m]  : (_Float16)0.0f;
  }
  __syncthreads();
  {
    const int ko = quad * 8;
    half8 af[4], bd[4];
    #pragma unroll
    for (int im = 0; im < 4; ++im)
      af[im] = *(const half8*)&sA[(wm + im * 16 + lr) * 32 + ko];
    #pragma unroll
    for (int in = 0; in < 4; ++in)
      bd[in] = *(const half8*)&sB1[(wn + in * 16 + lr) * 32 + ko];
    #pragma unroll
    for (int im = 0; im < 4; ++im)
      #pragma unroll
      for (int in = 0; in < 4; ++in)
        accG[im][in] = __builtin_amdgcn_mfma_f32_16x16x32_f16(af[im], bd[in], accG[im][in], 0, 0, 0);
  }

  // Epilogue: t = silu(gate) * up
  #pragma unroll
  for (int im = 0; im < 4; ++im)
    #pragma unroll
    for (int in = 0; in < 4; ++in) {
      const int growb = gm0 + wm + im * 16 + quad * 4;
      const int gcol  = gn0 + wn + in * 16 + lr;
      #pragma unroll
      for (int r = 0; r < 4; ++r) {
        float g = accG[im][in][r];
        float u = accU[im][in][r];
        float s = g / (1.0f + __expf(-g));
        tmat[(size_t)(growb + r) * D_FFN + gcol] = (_Float16)(s * u);
      }
    }
}

// ---------------------------------------------------------------------------
// Kernel 3: out = hidden_states + t @ Wd^T   (K = 8192), fp32 out.
// ---------------------------------------------------------------------------
__global__ __launch_bounds__(256, 2) void gemm_down(
    const _Float16* __restrict__ tmat, const float* __restrict__ Wd,
    const float* __restrict__ hs, float* __restrict__ out)
{
  __shared__ __align__(16) _Float16 sA[128*64];
  __shared__ __align__(16) _Float16 sB[128*64];

  const int tid  = threadIdx.x;
  const int lane = tid & 63;
  const int wv   = tid >> 6;
  const int wm   = (wv >> 1) * 64;
  const int wn   = (wv & 1) * 64;
  const int lr   = lane & 15;
  const int quad = lane >> 4;
  const int gm0  = blockIdx.y * 128;
  const int gn0  = blockIdx.x * 128;

  f32x4 acc[4][4];
  #pragma unroll
  for (int i = 0; i < 4; ++i)
    #pragma unroll
    for (int j = 0; j < 4; ++j) {
      f32x4 z = {0.f, 0.f, 0.f, 0.f};
      acc[i][j] = z;
    }

  for (int kt = 0; kt < D_FFN / 64; ++kt) {
    __syncthreads();
    const _Float16* Ab = tmat + (size_t)gm0 * D_FFN + kt * 64;
    #pragma unroll
    for (int j = 0; j < 4; ++j) {
      int idx = j * 256 + tid;
      int row = idx >> 3, c16 = idx & 7;
      async_load16(Ab + (size_t)row * D_FFN + c16 * 8, &sA[idx * 8]);
    }
    const float* Wt = Wd + (size_t)gn0 * D_FFN + kt * 64;
    #pragma unroll
    for (int i = 0; i < 8; ++i) {
      int idx = i * 256 + tid;
      int row = idx >> 4, c4 = idx & 15;
      f32x4 v = *(const f32x4*)(Wt + (size_t)row * D_FFN + c4 * 4);
      half4 h4;
      #pragma unroll
      for (int j = 0; j < 4; ++j) h4[j] = (_Float16)v[j];
      *(half4*)&sB[row * 64 + c4 * 4] = h4;
    }
    __syncthreads();
    #pragma unroll
    for (int ks = 0; ks < 2; ++ks) {
      const int ko = ks * 32 + quad * 8;
      half8 af[4], bf_[4];
      #pragma unroll
      for (int im = 0; im < 4; ++im)
        af[im] = *(const half8*)&sA[(wm + im * 16 + lr) * 64 + ko];
      #pragma unroll
      for (int in = 0; in < 4; ++in)
        bf_[in] = *(const half8*)&sB[(wn + in * 16 + lr) * 64 + ko];
      #pragma unroll
      for (int im = 0; im < 4; ++im)
        #pragma unroll
        for (int in = 0; in < 4; ++in)
          acc[im][in] = __builtin_amdgcn_mfma_f32_16x16x32_f16(af[im], bf_[in], acc[im][in], 0, 0, 0);
    }
  }

  #pragma unroll
  for (int im = 0; im < 4; ++im)
    #pragma unroll
    for (int in = 0; in < 4; ++in) {
      const int growb = gm0 + wm + im * 16 + quad * 4;
      const int gcol  = gn0 + wn + in * 16 + lr;
      #pragma unroll
      for (int r = 0; r < 4; ++r) {
        size_t o = (size_t)(growb + r) * D_MODEL + gcol;
        out[o] = hs[o] + acc[im][in][r];
      }
    }
}

extern "C" void kernel_launch(void* const* d_in, const int* in_sizes, int n_in,
                              void* d_out, int out_size, void* d_ws, size_t ws_size,
                              hipStream_t stream) {
  const float* hs    = (const float*)d_in[0];
  const float* attn  = (const float*)d_in[1];
  const float* Amat  = (const float*)d_in[2];
  const float* Bmat  = (const float*)d_in[3];
  const float* Wg    = (const float*)d_in[4];
  const float* Wu    = (const float*)d_in[5];
  const float* Wd    = (const float*)d_in[6];
  const float* gamma = (const float*)d_in[7];
  float* out = (float*)d_out;

  const int M = in_sizes[0] / D_MODEL;   // 4096 tokens

  char* ws = (char*)d_ws;
  _Float16* h16 = (_Float16*)ws;                                   // M*D*2  = 16.78 MB
  float*    cmat = (float*)(ws + (size_t)M * D_MODEL * 2);         // M*16*4 = 0.26 MB
  _Float16* tmat = (_Float16*)(ws + (size_t)M * D_MODEL * 2
                                  + (size_t)M * RANK * 4);         // M*F*2  = 67.1 MB

  prep_kernel<<<M, 256, 0, stream>>>(hs, attn, Amat, gamma, h16, cmat);
  gemm_gateup<<<dim3(D_FFN / 128, M / 128), 256, 0, stream>>>(h16, Wg, Wu, cmat, Bmat, tmat);
  gemm_down<<<dim3(D_MODEL / 128, M / 128), 256, 0, stream>>>(tmat, Wd, hs, out);
}

// Round 2
// 776.911 us; speedup vs baseline: 1.7526x; 1.7526x over previous
//
#include <hip/hip_runtime.h>
#include <cstdint>
#include <cstddef>

#define D_MODEL 2048
#define D_FFN   8192
#define RANK    16
#define EPS     1e-6f
#define MOD_SCALE 0.1f

typedef float    f32x4 __attribute__((ext_vector_type(4)));
typedef _Float16 half8 __attribute__((ext_vector_type(8)));
typedef _Float16 half4 __attribute__((ext_vector_type(4)));

// Async global->LDS, 16B per lane. LDS dest is wave-uniform base + lane*16;
// the GLOBAL address is per-lane, which lets us XOR-swizzle the source chunk
// (c ^ (row&7)) for bank-conflict-free ds_read_b128 later, at zero cost
// (permutation stays within a 128B segment -> still fully coalesced).
__device__ __forceinline__ void async_load16(const void* g, void* l) {
  __builtin_amdgcn_global_load_lds(
      (const __attribute__((address_space(1))) uint32_t*)g,
      (__attribute__((address_space(3))) uint32_t*)l,
      16, 0, 0);
}

// Stage a 128x64 f16 tile (row-major, stride `stride` halves) into lds,
// swizzled: LDS[row][p] holds global chunk p ^ (row&7)  (chunks = 8 halves).
__device__ __forceinline__ void stage_tile(const _Float16* __restrict__ gbase,
                                           size_t stride, _Float16* lds, int tid) {
  #pragma unroll
  for (int j = 0; j < 4; ++j) {
    int idx = j * 256 + tid;          // 0..1023 chunks
    int row = idx >> 3;
    int c   = (idx & 7) ^ (row & 7);  // swizzled global chunk
    async_load16(gbase + (size_t)row * stride + c * 8, &lds[idx * 8]);
  }
}

// Read the 8-half fragment for row r, chunk c from a swizzled tile.
__device__ __forceinline__ half8 frag_read(const _Float16* lds, int r, int c) {
  return *(const half8*)&lds[r * 64 + ((c ^ (r & 7)) * 8)];
}

// ---------------------------------------------------------------------------
// fp32 -> f16 elementwise convert, 8 elements/thread.
// ---------------------------------------------------------------------------
__global__ __launch_bounds__(256) void convert_f32_f16(
    const float* __restrict__ s, _Float16* __restrict__ d)
{
  size_t i = ((size_t)blockIdx.x * 256 + threadIdx.x) * 8;
  f32x4 a = *(const f32x4*)(s + i);
  f32x4 b = *(const f32x4*)(s + i + 4);
  half8 h;
  #pragma unroll
  for (int j = 0; j < 4; ++j) { h[j] = (_Float16)a[j]; h[4+j] = (_Float16)b[j]; }
  *(half8*)(d + i) = h;
}

// ---------------------------------------------------------------------------
// Kernel 1: per-token RMSNorm -> h (f16), and
//           c[m,r] = (h.A)[r] * 0.1*tanh((attn.A)[r])
// ---------------------------------------------------------------------------
__global__ __launch_bounds__(256) void prep_kernel(
    const float* __restrict__ hs, const float* __restrict__ attn,
    const float* __restrict__ Amat, const float* __restrict__ gamma,
    _Float16* __restrict__ h16, float* __restrict__ cmat)
{
  const int token = blockIdx.x;
  const int tid   = threadIdx.x;
  const int lane  = tid & 63;
  const int wv    = tid >> 6;
  const size_t tb = (size_t)token * D_MODEL;
  const int base  = tid * 8;

  f32x4 x0 = *(const f32x4*)(hs + tb + base);
  f32x4 x1 = *(const f32x4*)(hs + tb + base + 4);
  f32x4 a0 = *(const f32x4*)(attn + tb + base);
  f32x4 a1 = *(const f32x4*)(attn + tb + base + 4);

  float ss = 0.f;
  #pragma unroll
  for (int j = 0; j < 4; ++j) ss += x0[j]*x0[j] + x1[j]*x1[j];
  #pragma unroll
  for (int off = 32; off > 0; off >>= 1) ss += __shfl_xor(ss, off, 64);

  __shared__ float red[4];
  __shared__ float redp[4][RANK];
  __shared__ float redh[4][RANK];
  if (lane == 0) red[wv] = ss;
  __syncthreads();
  const float tot = red[0] + red[1] + red[2] + red[3];
  const float rms = rsqrtf(tot * (1.0f / D_MODEL) + EPS);

  f32x4 g0 = *(const f32x4*)(gamma + base);
  f32x4 g1 = *(const f32x4*)(gamma + base + 4);
  float hv[8], av[8];
  #pragma unroll
  for (int j = 0; j < 4; ++j) {
    hv[j]   = x0[j] * rms * g0[j];
    hv[4+j] = x1[j] * rms * g1[j];
    av[j]   = a0[j];
    av[4+j] = a1[j];
  }
  half8 hh;
  #pragma unroll
  for (int j = 0; j < 8; ++j) hh[j] = (_Float16)hv[j];
  *(half8*)(h16 + tb + base) = hh;

  float pa[RANK], ph[RANK];
  #pragma unroll
  for (int r = 0; r < RANK; ++r) { pa[r] = 0.f; ph[r] = 0.f; }
  #pragma unroll
  for (int e = 0; e < 8; ++e) {
    const f32x4* Ar = (const f32x4*)(Amat + (size_t)(base + e) * RANK);
    #pragma unroll
    for (int q = 0; q < 4; ++q) {
      f32x4 ar = Ar[q];
      #pragma unroll
      for (int j = 0; j < 4; ++j) {
        pa[q*4+j] += av[e] * ar[j];
        ph[q*4+j] += hv[e] * ar[j];
      }
    }
  }
  #pragma unroll
  for (int r = 0; r < RANK; ++r) {
    #pragma unroll
    for (int off = 32; off > 0; off >>= 1) {
      pa[r] += __shfl_xor(pa[r], off, 64);
      ph[r] += __shfl_xor(ph[r], off, 64);
    }
  }
  if (lane == 0) {
    #pragma unroll
    for (int r = 0; r < RANK; ++r) { redp[wv][r] = pa[r]; redh[wv][r] = ph[r]; }
  }
  __syncthreads();
  if (tid < RANK) {
    float sp = redp[0][tid] + redp[1][tid] + redp[2][tid] + redp[3][tid];
    float sh = redh[0][tid] + redh[1][tid] + redh[2][tid] + redh[3][tid];
    cmat[(size_t)token * RANK + tid] = sh * (MOD_SCALE * tanhf(sp));
  }
}

// ---------------------------------------------------------------------------
// Kernel 2: dual GEMM  gate = h@Wg16^T (+ rank-16 delta), up = h@Wu16^T;
//           t = silu(gate)*up (f16). 128x128 tile, BK=64, all-async staging.
// ---------------------------------------------------------------------------
__global__ __launch_bounds__(256, 2) void gemm_gateup(
    const _Float16* __restrict__ h16,
    const _Float16* __restrict__ Wg16, const _Float16* __restrict__ Wu16,
    const float* __restrict__ cmat, const float* __restrict__ Bmat,
    _Float16* __restrict__ tmat)
{
  __shared__ __align__(16) _Float16 sA [128*64];
  __shared__ __align__(16) _Float16 sB1[128*64];
  __shared__ __align__(16) _Float16 sB2[128*64];

  const int tid  = threadIdx.x;
  const int lane = tid & 63;
  const int wv   = tid >> 6;
  const int wm   = (wv >> 1) * 64;
  const int wn   = (wv & 1) * 64;
  const int lr   = lane & 15;
  const int quad = lane >> 4;
  const int gm0  = blockIdx.y * 128;
  const int gn0  = blockIdx.x * 128;

  f32x4 accG[4][4], accU[4][4];
  #pragma unroll
  for (int i = 0; i < 4; ++i)
    #pragma unroll
    for (int j = 0; j < 4; ++j) {
      f32x4 z = {0.f, 0.f, 0.f, 0.f};
      accG[i][j] = z; accU[i][j] = z;
    }

  for (int kt = 0; kt < D_MODEL / 64; ++kt) {
    __syncthreads();
    stage_tile(h16  + (size_t)gm0 * D_MODEL + kt * 64, D_MODEL, sA,  tid);
    stage_tile(Wg16 + (size_t)gn0 * D_MODEL + kt * 64, D_MODEL, sB1, tid);
    stage_tile(Wu16 + (size_t)gn0 * D_MODEL + kt * 64, D_MODEL, sB2, tid);
    __syncthreads();
    #pragma unroll
    for (int ks = 0; ks < 2; ++ks) {
      const int ck = ks * 4 + quad;         // 8-half chunk index along K
      half8 af[4], bg[4], bu[4];
      #pragma unroll
      for (int im = 0; im < 4; ++im)
        af[im] = frag_read(sA, wm + im * 16 + lr, ck);
      #pragma unroll
      for (int in = 0; in < 4; ++in) {
        bg[in] = frag_read(sB1, wn + in * 16 + lr, ck);
        bu[in] = frag_read(sB2, wn + in * 16 + lr, ck);
      }
      #pragma unroll
      for (int im = 0; im < 4; ++im)
        #pragma unroll
        for (int in = 0; in < 4; ++in) {
          accG[im][in] = __builtin_amdgcn_mfma_f32_16x16x32_f16(af[im], bg[in], accG[im][in], 0, 0, 0);
          accU[im][in] = __builtin_amdgcn_mfma_f32_16x16x32_f16(af[im], bu[in], accU[im][in], 0, 0, 0);
        }
    }
  }

  // rank-16 delta folded in as one zero-padded K=32 MFMA step into accG.
  __syncthreads();
  #pragma unroll
  for (int i = 0; i < 16; ++i) {
    int idx = i * 256 + tid;              // 0..4095
    int m = idx >> 5, kk = idx & 31;
    sA[idx]  = (kk < RANK) ? (_Float16)cmat[(size_t)(gm0 + m) * RANK + kk] : (_Float16)0.0f;
    sB1[idx] = (kk < RANK) ? (_Float16)Bmat[(size_t)kk * D_FFN + gn0 + m]  : (_Float16)0.0f;
  }
  __syncthreads();
  {
    const int ko = quad * 8;
    half8 af[4], bd[4];
    #pragma unroll
    for (int im = 0; im < 4; ++im)
      af[im] = *(const half8*)&sA[(wm + im * 16 + lr) * 32 + ko];
    #pragma unroll
    for (int in = 0; in < 4; ++in)
      bd[in] = *(const half8*)&sB1[(wn + in * 16 + lr) * 32 + ko];
    #pragma unroll
    for (int im = 0; im < 4; ++im)
      #pragma unroll
      for (int in = 0; in < 4; ++in)
        accG[im][in] = __builtin_amdgcn_mfma_f32_16x16x32_f16(af[im], bd[in], accG[im][in], 0, 0, 0);
  }

  // Epilogue: t = silu(gate) * up
  #pragma unroll
  for (int im = 0; im < 4; ++im)
    #pragma unroll
    for (int in = 0; in < 4; ++in) {
      const int growb = gm0 + wm + im * 16 + quad * 4;
      const int gcol  = gn0 + wn + in * 16 + lr;
      #pragma unroll
      for (int r = 0; r < 4; ++r) {
        float g = accG[im][in][r];
        float u = accU[im][in][r];
        float s = g / (1.0f + __expf(-g));
        tmat[(size_t)(growb + r) * D_FFN + gcol] = (_Float16)(s * u);
      }
    }
}

// ---------------------------------------------------------------------------
// Kernel 3: out = hidden_states + t @ Wd16^T   (K = 8192), fp32 out.
// ---------------------------------------------------------------------------
__global__ __launch_bounds__(256, 2) void gemm_down(
    const _Float16* __restrict__ tmat, const _Float16* __restrict__ Wd16,
    const float* __restrict__ hs, float* __restrict__ out)
{
  __shared__ __align__(16) _Float16 sA[128*64];
  __shared__ __align__(16) _Float16 sB[128*64];

  const int tid  = threadIdx.x;
  const int lane = tid & 63;
  const int wv   = tid >> 6;
  const int wm   = (wv >> 1) * 64;
  const int wn   = (wv & 1) * 64;
  const int lr   = lane & 15;
  const int quad = lane >> 4;
  const int gm0  = blockIdx.y * 128;
  const int gn0  = blockIdx.x * 128;

  f32x4 acc[4][4];
  #pragma unroll
  for (int i = 0; i < 4; ++i)
    #pragma unroll
    for (int j = 0; j < 4; ++j) {
      f32x4 z = {0.f, 0.f, 0.f, 0.f};
      acc[i][j] = z;
    }

  for (int kt = 0; kt < D_FFN / 64; ++kt) {
    __syncthreads();
    stage_tile(tmat + (size_t)gm0 * D_FFN + kt * 64, D_FFN, sA, tid);
    stage_tile(Wd16 + (size_t)gn0 * D_FFN + kt * 64, D_FFN, sB, tid);
    __syncthreads();
    #pragma unroll
    for (int ks = 0; ks < 2; ++ks) {
      const int ck = ks * 4 + quad;
      half8 af[4], bf_[4];
      #pragma unroll
      for (int im = 0; im < 4; ++im)
        af[im] = frag_read(sA, wm + im * 16 + lr, ck);
      #pragma unroll
      for (int in = 0; in < 4; ++in)
        bf_[in] = frag_read(sB, wn + in * 16 + lr, ck);
      #pragma unroll
      for (int im = 0; im < 4; ++im)
        #pragma unroll
        for (int in = 0; in < 4; ++in)
          acc[im][in] = __builtin_amdgcn_mfma_f32_16x16x32_f16(af[im], bf_[in], acc[im][in], 0, 0, 0);
    }
  }

  #pragma unroll
  for (int im = 0; im < 4; ++im)
    #pragma unroll
    for (int in = 0; in < 4; ++in) {
      const int growb = gm0 + wm + im * 16 + quad * 4;
      const int gcol  = gn0 + wn + in * 16 + lr;
      #pragma unroll
      for (int r = 0; r < 4; ++r) {
        size_t o = (size_t)(growb + r) * D_MODEL + gcol;
        out[o] = hs[o] + acc[im][in][r];
      }
    }
}

extern "C" void kernel_launch(void* const* d_in, const int* in_sizes, int n_in,
                              void* d_out, int out_size, void* d_ws, size_t ws_size,
                              hipStream_t stream) {
  const float* hs    = (const float*)d_in[0];
  const float* attn  = (const float*)d_in[1];
  const float* Amat  = (const float*)d_in[2];
  const float* Bmat  = (const float*)d_in[3];
  const float* Wg    = (const float*)d_in[4];
  const float* Wu    = (const float*)d_in[5];
  const float* Wd    = (const float*)d_in[6];
  const float* gamma = (const float*)d_in[7];
  float* out = (float*)d_out;

  const int M = in_sizes[0] / D_MODEL;   // 4096 tokens
  const size_t WD = (size_t)D_FFN * D_MODEL;  // 16,777,216 elements per weight

  // ws layout (peak 151.3 MB):
  //   h16   M*D f16      = 16.78 MB
  //   cmat  M*16 f32     =  0.26 MB
  //   tmat  M*F f16      = 67.11 MB
  //   wbuf  2*F*D f16    = 67.11 MB  (Wg16|Wu16 for gateup; Wd16 reuses Wg16
  //                                   slot after gateup has consumed it)
  char* ws = (char*)d_ws;
  _Float16* h16  = (_Float16*)ws;
  float*    cmat = (float*)(ws + (size_t)M * D_MODEL * 2);
  _Float16* tmat = (_Float16*)(ws + (size_t)M * D_MODEL * 2 + (size_t)M * RANK * 4);
  _Float16* wbuf = tmat + (size_t)M * D_FFN;
  _Float16* Wg16 = wbuf;
  _Float16* Wu16 = wbuf + WD;
  _Float16* Wd16 = wbuf;          // stream-ordered reuse

  const int convBlocks = (int)(WD / (256 * 8));   // 8192

  prep_kernel<<<M, 256, 0, stream>>>(hs, attn, Amat, gamma, h16, cmat);
  convert_f32_f16<<<convBlocks, 256, 0, stream>>>(Wg, Wg16);
  convert_f32_f16<<<convBlocks, 256, 0, stream>>>(Wu, Wu16);
  gemm_gateup<<<dim3(D_FFN / 128, M / 128), 256, 0, stream>>>(h16, Wg16, Wu16, cmat, Bmat, tmat);
  convert_f32_f16<<<convBlocks, 256, 0, stream>>>(Wd, Wd16);
  gemm_down<<<dim3(D_MODEL / 128, M / 128), 256, 0, stream>>>(tmat, Wd16, hs, out);
}